// Round 6
// baseline (594.109 us; speedup 1.0000x reference)
//
#include <hip/hip_runtime.h>

// ---------------------------------------------------------------------------
// 2-layer GCN: out = A_norm @ relu(A_norm @ (x@W1) + b1) @ W2 (+b2)
// A_norm = D^-1/2 (A+I) D^-1/2, factored: out[d] = dinv[d]*sum_src(g[src]) + b
// with g = dinv * (x @ W).
//
// R1: two-level counting-sort CSR build (killed 198 MB scatter-write amp).
// R2: G stored bf16 (aggregate is L3-fetch-bound; halve the payload).
// R3/R4: MFMA bf16 GEMM (split-A ~f32 precision), packed 4 B pairs, bf16 act.
// R5: (a) radix CSR build: per-tile hist matrix + column scan -> single-pass
//         partition (one read of dst, one LDS-atomic pass, -1 kernel);
//     (b) agg1 fused with gemm2 (act never hits HBM; MFMA hides in gather
//         stalls — MFMA/VALU pipes are independent);
//     (c) gemm1 loads A-frags direct from global (rows are wave-private);
//     (d) nontemporal srcs loads / out stores (don't evict G from L2).
// Requires N <= 131072 (17-bit src in packed pairs).
// ---------------------------------------------------------------------------

#define NPB 128          // nodes per bucket (dst >> 7)
#define NBMAX 1024       // supports N <= 131072
#define EPT 64           // edges per thread in partition/hist kernels
#define PART_TILE (256 * EPT)

typedef unsigned short ushort_t;
typedef __attribute__((ext_vector_type(8))) short short8;
typedef __attribute__((ext_vector_type(4))) float f32x4;

__device__ __forceinline__ unsigned short f32_to_bf16_rne(float x) {
    unsigned int v = __float_as_uint(x);
    unsigned int r = v + 0x7fffu + ((v >> 16) & 1u);
    return (unsigned short)(r >> 16);
}

// W (f32, [k][n]) -> Wprep (bf16, [n][k]) for both layers. 2*16384 elems.
__global__ __launch_bounds__(256) void k_wprep(
    const float* __restrict__ W1, const float* __restrict__ W2,
    ushort_t* __restrict__ Wp1, ushort_t* __restrict__ Wp2) {
    int idx = blockIdx.x * 256 + threadIdx.x;
    int which = idx >> 14;
    int e = idx & 16383;
    int n = e & 127, k = e >> 7;
    const float* W = which ? W2 : W1;
    ushort_t* Wp = which ? Wp2 : Wp1;
    Wp[n * 128 + k] = f32_to_bf16_rne(W[k * 128 + n]);
}

// Radix pass 0: per-tile bucket histogram -> C[tile][b].
__global__ __launch_bounds__(256) void k_hist_tiles(
    const int* __restrict__ dst, int* __restrict__ C,
    int e, int nbp, int total) {
    __shared__ int hist[NBMAX];
    int t = threadIdx.x;
    int tile = blockIdx.x;
    for (int k = t; k < nbp; k += 256) hist[k] = 0;
    __syncthreads();
    int t0 = tile * PART_TILE;
#pragma unroll 4
    for (int j = 0; j < EPT; j++) {
        int i = t0 + j * 256 + t;
        if (i < total) {
            int d = (i < e) ? dst[i] : (i - e);
            atomicAdd(&hist[d >> 7], 1);
        }
    }
    __syncthreads();
    int* row = C + (size_t)tile * nbp;
    for (int k = t; k < nbp; k += 256) row[k] = hist[k];
}

// Radix pass 1: column-wise exclusive scan of C over tiles; colsum[b] = total.
__global__ __launch_bounds__(256) void k_col_scan(
    int* __restrict__ C, int* __restrict__ colsum, int T, int nbp) {
    int b = blockIdx.x * 256 + threadIdx.x;
    if (b >= nbp) return;
    int running = 0;
    int t = 0;
    for (; t + 8 <= T; t += 8) {
        int v[8];
#pragma unroll
        for (int j = 0; j < 8; j++) v[j] = C[(size_t)(t + j) * nbp + b];
#pragma unroll
        for (int j = 0; j < 8; j++) {
            C[(size_t)(t + j) * nbp + b] = running;
            running += v[j];
        }
    }
    for (; t < T; t++) {
        int v = C[(size_t)t * nbp + b];
        C[(size_t)t * nbp + b] = running;
        running += v;
    }
    colsum[b] = running;
}

// Exclusive scan of colsum -> bucket_ptr. 1 WG, nbp <= 1024.
__global__ __launch_bounds__(256) void k_bucket_scan(
    const int* __restrict__ colsum, int* __restrict__ bucket_ptr,
    int nbp, int total) {
    __shared__ int sd[256];
    int t = threadIdx.x;
    int c[4];
#pragma unroll
    for (int j = 0; j < 4; j++) {
        int k = t * 4 + j;
        c[j] = (k < nbp) ? colsum[k] : 0;
    }
    int s = c[0] + c[1] + c[2] + c[3];
    sd[t] = s;
    __syncthreads();
    for (int off = 1; off < 256; off <<= 1) {
        int v = (t >= off) ? sd[t - off] : 0;
        __syncthreads();
        sd[t] += v;
        __syncthreads();
    }
    int pre = sd[t] - s;
#pragma unroll
    for (int j = 0; j < 4; j++) {
        int k = t * 4 + j;
        if (k < nbp) bucket_ptr[k] = pre;
        pre += c[j];
    }
    if (t == 255) bucket_ptr[nbp] = total;
}

// Radix pass 2: single-pass partition. LDS cursor = C[tile][b] + bucket_ptr[b].
__global__ __launch_bounds__(256) void k_partition(
    const int* __restrict__ src, const int* __restrict__ dst,
    const int* __restrict__ C, const int* __restrict__ bucket_ptr,
    unsigned int* __restrict__ pairs, int e, int nbp, int total) {
    __shared__ int lcur[NBMAX];
    int t = threadIdx.x;
    int tile = blockIdx.x;
    const int* row = C + (size_t)tile * nbp;
    for (int k = t; k < nbp; k += 256) lcur[k] = row[k] + bucket_ptr[k];
    __syncthreads();
    int t0 = tile * PART_TILE;
#pragma unroll 4
    for (int j = 0; j < EPT; j++) {
        int i = t0 + j * 256 + t;
        if (i < total) {
            int s, d;
            if (i < e) { s = src[i]; d = dst[i]; }
            else       { s = i - e;  d = s; }
            int b = d >> 7;
            int off = atomicAdd(&lcur[b], 1);
            pairs[off] = (unsigned int)s | ((unsigned int)(d & 127) << 17);
        }
    }
}

// Pass 3: one WG per bucket; LDS-only counts/scan/row_ptr/dinv/fine-sort.
__global__ __launch_bounds__(256) void k_build(
    const unsigned int* __restrict__ pairs, const int* __restrict__ bucket_ptr,
    int* __restrict__ row_ptr, int* __restrict__ srcs,
    float* __restrict__ dinv, int n) {
    __shared__ int cnt[NPB];
    __shared__ int scn[NPB];
    __shared__ int cur[NPB];
    int b = blockIdx.x;
    int t = threadIdx.x;
    int node0 = b << 7;
    int p0 = bucket_ptr[b], p1 = bucket_ptr[b + 1];
    if (t < NPB) cnt[t] = 0;
    __syncthreads();
    for (int i = p0 + t; i < p1; i += 256) {
        int dlow = (int)(pairs[i] >> 17) & 127;
        atomicAdd(&cnt[dlow], 1);
    }
    __syncthreads();
    if (t < NPB) scn[t] = cnt[t];
    __syncthreads();
    for (int off = 1; off < NPB; off <<= 1) {
        int v = (t < NPB && t >= off) ? scn[t - off] : 0;
        __syncthreads();
        if (t < NPB) scn[t] += v;
        __syncthreads();
    }
    if (t < NPB) {
        int incl = scn[t];
        int excl = incl - cnt[t];
        int start = p0 + excl;
        cur[t] = start;
        int node = node0 + t;
        if (node < n) {
            row_ptr[node] = start;
            dinv[node] = rsqrtf((float)cnt[t]);  // deg >= 1 (self-loop)
            if (node == n - 1) row_ptr[n] = p0 + incl;
        }
    }
    __syncthreads();
    for (int i = p0 + t; i < p1; i += 256) {
        unsigned int pr = pairs[i];
        int pos = atomicAdd(&cur[(pr >> 17) & 127], 1);
        srcs[pos] = (int)(pr & 0x1FFFFu);
    }
}

// ---------------------------------------------------------------------------
// GEMM1: G[r][:] = bf16( dinv[r] * (A @ W)[r][:] ), A: Mx128 f32 (split-A).
// No LDS: each wave's 16 A-rows are private -> load fragments from global.
// mfma_f32_16x16x32_bf16 layouts (HW-verified, guide m89/m91):
//   A: lane holds A[m=lane&15][k=(lane>>4)*8 + j]
//   B: lane holds B[k=(lane>>4)*8 + j][n=lane&15]   (Wp is [n][k] bf16)
//   C/D: col=lane&15, row=(lane>>4)*4 + reg
// ---------------------------------------------------------------------------
__global__ __launch_bounds__(256) void k_gemm1(
    const float* __restrict__ A, const ushort_t* __restrict__ Wp,
    const float* __restrict__ dinv, ushort_t* __restrict__ G, int M) {
    int t = threadIdx.x;
    int row0 = blockIdx.x * 64;
    int wv = t >> 6;
    int lane = t & 63;
    int m = lane & 15;
    int quad = lane >> 4;

    int gr_row = row0 + wv * 16 + m;
    int gcl = gr_row < M ? gr_row : M - 1;
    const float* ap = A + (size_t)gcl * 128 + quad * 8;

    f32x4 acc[8];
#pragma unroll
    for (int c = 0; c < 8; c++) acc[c] = (f32x4){0.f, 0.f, 0.f, 0.f};

#pragma unroll
    for (int ks = 0; ks < 4; ks++) {
        int kb = ks * 32 + quad * 8;
        float xs[8];
        *(float4*)&xs[0] = *(const float4*)(ap + ks * 32);
        *(float4*)&xs[4] = *(const float4*)(ap + ks * 32 + 4);
        short8 ahi, alo;
#pragma unroll
        for (int j = 0; j < 8; j++) {
            unsigned short h = f32_to_bf16_rne(xs[j]);
            ahi[j] = (short)h;
            float hf = __uint_as_float((unsigned int)h << 16);
            alo[j] = (short)f32_to_bf16_rne(xs[j] - hf);
        }
#pragma unroll
        for (int c = 0; c < 8; c++) {
            short8 b8 = *(const short8*)(Wp + (size_t)(c * 16 + m) * 128 + kb);
            acc[c] = __builtin_amdgcn_mfma_f32_16x16x32_bf16(ahi, b8, acc[c], 0, 0, 0);
            acc[c] = __builtin_amdgcn_mfma_f32_16x16x32_bf16(alo, b8, acc[c], 0, 0, 0);
        }
    }

    int rbase = row0 + wv * 16 + quad * 4;
#pragma unroll
    for (int reg = 0; reg < 4; reg++) {
        int gr = rbase + reg;
        if (gr < M) {
            float dv = dinv[gr];
#pragma unroll
            for (int c = 0; c < 8; c++)
                G[(size_t)gr * 128 + c * 16 + m] = f32_to_bf16_rne(acc[c][reg] * dv);
        }
    }
}

// ---------------------------------------------------------------------------
// Fused agg1+gemm2: block = 16 nodes, 4 waves. Each wave gathers 4 nodes
// (2 ch/lane) -> act = relu(dinv*sum + b1) -> bf16 pair into LDS tile ->
// MFMA act-tile @ W2 (wave w: channels 32w..32w+31) -> g2 = bf16(dinv * .).
// ---------------------------------------------------------------------------
__global__ __launch_bounds__(256) void k_agg1_gemm2(
    const int* __restrict__ row_ptr, const int* __restrict__ srcs,
    const ushort_t* __restrict__ G1, const float* __restrict__ dinv,
    const float* __restrict__ b1, const ushort_t* __restrict__ Wp2,
    ushort_t* __restrict__ G2, int n) {
    __shared__ unsigned int ActU[16][68];  // 16 nodes x 64 bf16-pairs (+pad)

    int t = threadIdx.x;
    int wv = t >> 6;
    int lane = t & 63;
    int base = blockIdx.x * 16;
    int c = lane * 2;

    // ---- gather phase: wave wv handles nodes base + wv*4 .. +3 ----
#pragma unroll
    for (int i = 0; i < 4; i++) {
        int nl = wv * 4 + i;
        int node = base + nl;
        float a0 = 0.f, a1 = 0.f;
        if (node < n) {
            int beg = row_ptr[node], end = row_ptr[node + 1];
            int p = beg;
            for (; p + 4 <= end; p += 4) {
                int s0 = __builtin_nontemporal_load(&srcs[p]);
                int s1 = __builtin_nontemporal_load(&srcs[p + 1]);
                int s2 = __builtin_nontemporal_load(&srcs[p + 2]);
                int s3 = __builtin_nontemporal_load(&srcs[p + 3]);
                unsigned int u0 = *(const unsigned int*)(G1 + (size_t)s0 * 128 + c);
                unsigned int u1 = *(const unsigned int*)(G1 + (size_t)s1 * 128 + c);
                unsigned int u2 = *(const unsigned int*)(G1 + (size_t)s2 * 128 + c);
                unsigned int u3 = *(const unsigned int*)(G1 + (size_t)s3 * 128 + c);
                a0 += __uint_as_float(u0 << 16) + __uint_as_float(u1 << 16) +
                      __uint_as_float(u2 << 16) + __uint_as_float(u3 << 16);
                a1 += __uint_as_float(u0 & 0xffff0000u) + __uint_as_float(u1 & 0xffff0000u) +
                      __uint_as_float(u2 & 0xffff0000u) + __uint_as_float(u3 & 0xffff0000u);
            }
            for (; p < end; p++) {
                int s = __builtin_nontemporal_load(&srcs[p]);
                unsigned int u = *(const unsigned int*)(G1 + (size_t)s * 128 + c);
                a0 += __uint_as_float(u << 16);
                a1 += __uint_as_float(u & 0xffff0000u);
            }
            float dv = dinv[node];
            a0 = fmaxf(fmaf(a0, dv, b1[c]), 0.f);
            a1 = fmaxf(fmaf(a1, dv, b1[c + 1]), 0.f);
        }
        ActU[nl][lane] = (unsigned int)f32_to_bf16_rne(a0) |
                         ((unsigned int)f32_to_bf16_rne(a1) << 16);
    }
    __syncthreads();

    // ---- MFMA phase: wave wv computes channels 32*wv .. 32*wv+31 ----
    int m = lane & 15;
    int quad = lane >> 4;
    f32x4 acc[2];
    acc[0] = (f32x4){0.f, 0.f, 0.f, 0.f};
    acc[1] = (f32x4){0.f, 0.f, 0.f, 0.f};
#pragma unroll
    for (int ks = 0; ks < 4; ks++) {
        int kb = ks * 32 + quad * 8;
        short8 a8 = *(const short8*)&ActU[m][ks * 16 + quad * 4];
#pragma unroll
        for (int cl = 0; cl < 2; cl++) {
            int ct = wv * 2 + cl;
            short8 b8 = *(const short8*)(Wp2 + (size_t)(ct * 16 + m) * 128 + kb);
            acc[cl] = __builtin_amdgcn_mfma_f32_16x16x32_bf16(a8, b8, acc[cl], 0, 0, 0);
        }
    }
#pragma unroll
    for (int reg = 0; reg < 4; reg++) {
        int gnode = base + quad * 4 + reg;
        if (gnode < n) {
            float dv = dinv[gnode];
#pragma unroll
            for (int cl = 0; cl < 2; cl++) {
                int ch = (wv * 2 + cl) * 16 + m;
                G2[(size_t)gnode * 128 + ch] = f32_to_bf16_rne(acc[cl][reg] * dv);
            }
        }
    }
}

// Final aggregate: gather g2, out = dinv*sum + b2 (f32, nontemporal store).
__global__ __launch_bounds__(256) void k_agg2(
    const int* __restrict__ row_ptr, const int* __restrict__ srcs,
    const ushort_t* __restrict__ G, const float* __restrict__ dinv,
    const float* __restrict__ bias, float* __restrict__ Out, int n) {
    int wid = (blockIdx.x * 256 + threadIdx.x) >> 6;
    int lane = threadIdx.x & 63;
    if (wid >= n) return;
    int beg = row_ptr[wid], end = row_ptr[wid + 1];
    int c = lane * 2;
    float a0 = 0.f, a1 = 0.f;
    int p = beg;
    for (; p + 4 <= end; p += 4) {
        int s0 = __builtin_nontemporal_load(&srcs[p]);
        int s1 = __builtin_nontemporal_load(&srcs[p + 1]);
        int s2 = __builtin_nontemporal_load(&srcs[p + 2]);
        int s3 = __builtin_nontemporal_load(&srcs[p + 3]);
        unsigned int u0 = *(const unsigned int*)(G + (size_t)s0 * 128 + c);
        unsigned int u1 = *(const unsigned int*)(G + (size_t)s1 * 128 + c);
        unsigned int u2 = *(const unsigned int*)(G + (size_t)s2 * 128 + c);
        unsigned int u3 = *(const unsigned int*)(G + (size_t)s3 * 128 + c);
        a0 += __uint_as_float(u0 << 16) + __uint_as_float(u1 << 16) +
              __uint_as_float(u2 << 16) + __uint_as_float(u3 << 16);
        a1 += __uint_as_float(u0 & 0xffff0000u) + __uint_as_float(u1 & 0xffff0000u) +
              __uint_as_float(u2 & 0xffff0000u) + __uint_as_float(u3 & 0xffff0000u);
    }
    for (; p < end; p++) {
        int s = __builtin_nontemporal_load(&srcs[p]);
        unsigned int u = *(const unsigned int*)(G + (size_t)s * 128 + c);
        a0 += __uint_as_float(u << 16);
        a1 += __uint_as_float(u & 0xffff0000u);
    }
    float dv = dinv[wid];
    a0 = fmaf(a0, dv, bias[c]);
    a1 = fmaf(a1, dv, bias[c + 1]);
    unsigned long long uv = ((unsigned long long)__float_as_uint(a1) << 32) |
                            (unsigned long long)__float_as_uint(a0);
    __builtin_nontemporal_store(uv, (unsigned long long*)(Out + (size_t)wid * 128 + c));
}

extern "C" void kernel_launch(void* const* d_in, const int* in_sizes, int n_in,
                              void* d_out, int out_size, void* d_ws, size_t ws_size,
                              hipStream_t stream) {
    const float* x  = (const float*)d_in[0];
    const int*   ei = (const int*)d_in[1];
    const float* W1 = (const float*)d_in[2];
    const float* b1 = (const float*)d_in[3];
    const float* W2 = (const float*)d_in[4];
    const float* b2 = (const float*)d_in[5];
    float* out = (float*)d_out;

    const int C = 128;
    const int N = in_sizes[0] / C;
    const int E = in_sizes[1] / 2;
    const int* src = ei;
    const int* dst = ei + E;
    const int total = E + N;
    const int nbp = (N + NPB - 1) >> 7;             // buckets (782)
    const int T = (total + PART_TILE - 1) / PART_TILE;  // tiles (202)

    char* ws = (char*)d_ws;
    size_t off = 0;
    auto alloc = [&](size_t bytes) -> void* {
        void* p = ws + off;
        off = (off + bytes + 511) & ~(size_t)511;
        return p;
    };
    int*   Cmat       = (int*)alloc((size_t)T * nbp * 4);       // ~632 KB
    int*   colsum     = (int*)alloc((size_t)nbp * 4);
    int*   bucket_ptr = (int*)alloc((size_t)(nbp + 1) * 4);
    int*   row_ptr    = (int*)alloc(((size_t)N + 1) * 4);
    float* dinv       = (float*)alloc((size_t)N * 4);
    int*   srcs       = (int*)alloc((size_t)total * 4);
    ushort_t* Wp1     = (ushort_t*)alloc(128 * 128 * 2);
    ushort_t* Wp2     = (ushort_t*)alloc(128 * 128 * 2);
    ushort_t* G1      = (ushort_t*)alloc((size_t)N * C * 2);
    // G2 (N*C*2) shares with pairs (total*4): pairs dead after k_build.
    size_t g2b = (size_t)N * C * 2, pb = (size_t)total * 4;
    void* shared = alloc(g2b > pb ? g2b : pb);
    ushort_t* G2 = (ushort_t*)shared;
    unsigned int* pairs = (unsigned int*)shared;

    // ---- weight prep + radix CSR build ----
    k_wprep<<<128, 256, 0, stream>>>(W1, W2, Wp1, Wp2);
    k_hist_tiles<<<T, 256, 0, stream>>>(dst, Cmat, E, nbp, total);
    k_col_scan<<<(nbp + 255) / 256, 256, 0, stream>>>(Cmat, colsum, T, nbp);
    k_bucket_scan<<<1, 256, 0, stream>>>(colsum, bucket_ptr, nbp, total);
    k_partition<<<T, 256, 0, stream>>>(src, dst, Cmat, bucket_ptr, pairs, E, nbp, total);
    k_build<<<nbp, 256, 0, stream>>>(pairs, bucket_ptr, row_ptr, srcs, dinv, N);

    // ---- layer 1 GEMM: G1 = bf16(dinv*(x@W1)) ----
    k_gemm1<<<(N + 63) / 64, 256, 0, stream>>>(x, Wp1, dinv, G1, N);

    // ---- fused: act = relu(dinv*sum(G1)+b1); G2 = bf16(dinv*(act@W2)) ----
    k_agg1_gemm2<<<(N + 15) / 16, 256, 0, stream>>>(
        row_ptr, srcs, G1, dinv, b1, Wp2, G2, N);

    // ---- layer 2 aggregate: out = dinv*sum(G2) + b2 ----
    k_agg2<<<(N + 3) / 4, 256, 0, stream>>>(row_ptr, srcs, G2, dinv, b2, out, N);
}

// Round 7
// 518.694 us; speedup vs baseline: 1.1454x; 1.1454x over previous
//
#include <hip/hip_runtime.h>

// ---------------------------------------------------------------------------
// 2-layer GCN: out = A_norm @ relu(A_norm @ (x@W1) + b1) @ W2 (+b2)
// A_norm = D^-1/2 (A+I) D^-1/2, factored: out[d] = dinv[d]*sum_src(g[src]) + b
// with g = dinv * (x @ W).
//
// R1: two-level counting-sort CSR build (killed 198 MB scatter-write amp).
// R2: G stored bf16 (aggregate is L3-fetch-bound; halve the payload).
// R3/R4: MFMA bf16 GEMM (split-A ~f32 precision), packed 4 B pairs, bf16 act.
// R5: radix CSR (single-pass partition); gemm1 direct-from-global A-frags.
// R6: FAILED fusion of agg1+gemm2 (barrier serialization dropped gather BW
//     3.4->2.45 TB/s). R7 reverts it.
// R7: unfused agg1(bf16 out) + gemm2 (direct global loads, in-place act->G2,
//     per-wave-disjoint rows); unroll-8 gather MLP; nt store only on final out.
// Requires N <= 131072 (17-bit src in packed pairs).
// ---------------------------------------------------------------------------

#define NPB 128          // nodes per bucket (dst >> 7)
#define NBMAX 1024       // supports N <= 131072
#define EPT 64           // edges per thread in partition/hist kernels
#define PART_TILE (256 * EPT)

typedef unsigned short ushort_t;
typedef __attribute__((ext_vector_type(8))) short short8;
typedef __attribute__((ext_vector_type(4))) float f32x4;

__device__ __forceinline__ unsigned short f32_to_bf16_rne(float x) {
    unsigned int v = __float_as_uint(x);
    unsigned int r = v + 0x7fffu + ((v >> 16) & 1u);
    return (unsigned short)(r >> 16);
}

// W (f32, [k][n]) -> Wprep (bf16, [n][k]) for both layers. 2*16384 elems.
__global__ __launch_bounds__(256) void k_wprep(
    const float* __restrict__ W1, const float* __restrict__ W2,
    ushort_t* __restrict__ Wp1, ushort_t* __restrict__ Wp2) {
    int idx = blockIdx.x * 256 + threadIdx.x;
    int which = idx >> 14;
    int e = idx & 16383;
    int n = e & 127, k = e >> 7;
    const float* W = which ? W2 : W1;
    ushort_t* Wp = which ? Wp2 : Wp1;
    Wp[n * 128 + k] = f32_to_bf16_rne(W[k * 128 + n]);
}

// Radix pass 0: per-tile bucket histogram -> C[tile][b].
__global__ __launch_bounds__(256) void k_hist_tiles(
    const int* __restrict__ dst, int* __restrict__ C,
    int e, int nbp, int total) {
    __shared__ int hist[NBMAX];
    int t = threadIdx.x;
    int tile = blockIdx.x;
    for (int k = t; k < nbp; k += 256) hist[k] = 0;
    __syncthreads();
    int t0 = tile * PART_TILE;
#pragma unroll 4
    for (int j = 0; j < EPT; j++) {
        int i = t0 + j * 256 + t;
        if (i < total) {
            int d = (i < e) ? dst[i] : (i - e);
            atomicAdd(&hist[d >> 7], 1);
        }
    }
    __syncthreads();
    int* row = C + (size_t)tile * nbp;
    for (int k = t; k < nbp; k += 256) row[k] = hist[k];
}

// Radix pass 1: column-wise exclusive scan of C over tiles; colsum[b] = total.
__global__ __launch_bounds__(256) void k_col_scan(
    int* __restrict__ C, int* __restrict__ colsum, int T, int nbp) {
    int b = blockIdx.x * 256 + threadIdx.x;
    if (b >= nbp) return;
    int running = 0;
    int t = 0;
    for (; t + 8 <= T; t += 8) {
        int v[8];
#pragma unroll
        for (int j = 0; j < 8; j++) v[j] = C[(size_t)(t + j) * nbp + b];
#pragma unroll
        for (int j = 0; j < 8; j++) {
            C[(size_t)(t + j) * nbp + b] = running;
            running += v[j];
        }
    }
    for (; t < T; t++) {
        int v = C[(size_t)t * nbp + b];
        C[(size_t)t * nbp + b] = running;
        running += v;
    }
    colsum[b] = running;
}

// Exclusive scan of colsum -> bucket_ptr. 1 WG, nbp <= 1024.
__global__ __launch_bounds__(256) void k_bucket_scan(
    const int* __restrict__ colsum, int* __restrict__ bucket_ptr,
    int nbp, int total) {
    __shared__ int sd[256];
    int t = threadIdx.x;
    int c[4];
#pragma unroll
    for (int j = 0; j < 4; j++) {
        int k = t * 4 + j;
        c[j] = (k < nbp) ? colsum[k] : 0;
    }
    int s = c[0] + c[1] + c[2] + c[3];
    sd[t] = s;
    __syncthreads();
    for (int off = 1; off < 256; off <<= 1) {
        int v = (t >= off) ? sd[t - off] : 0;
        __syncthreads();
        sd[t] += v;
        __syncthreads();
    }
    int pre = sd[t] - s;
#pragma unroll
    for (int j = 0; j < 4; j++) {
        int k = t * 4 + j;
        if (k < nbp) bucket_ptr[k] = pre;
        pre += c[j];
    }
    if (t == 255) bucket_ptr[nbp] = total;
}

// Radix pass 2: single-pass partition. LDS cursor = C[tile][b] + bucket_ptr[b].
__global__ __launch_bounds__(256) void k_partition(
    const int* __restrict__ src, const int* __restrict__ dst,
    const int* __restrict__ C, const int* __restrict__ bucket_ptr,
    unsigned int* __restrict__ pairs, int e, int nbp, int total) {
    __shared__ int lcur[NBMAX];
    int t = threadIdx.x;
    int tile = blockIdx.x;
    const int* row = C + (size_t)tile * nbp;
    for (int k = t; k < nbp; k += 256) lcur[k] = row[k] + bucket_ptr[k];
    __syncthreads();
    int t0 = tile * PART_TILE;
#pragma unroll 4
    for (int j = 0; j < EPT; j++) {
        int i = t0 + j * 256 + t;
        if (i < total) {
            int s, d;
            if (i < e) { s = src[i]; d = dst[i]; }
            else       { s = i - e;  d = s; }
            int b = d >> 7;
            int off = atomicAdd(&lcur[b], 1);
            pairs[off] = (unsigned int)s | ((unsigned int)(d & 127) << 17);
        }
    }
}

// Pass 3: one WG per bucket; LDS-only counts/scan/row_ptr/dinv/fine-sort.
__global__ __launch_bounds__(256) void k_build(
    const unsigned int* __restrict__ pairs, const int* __restrict__ bucket_ptr,
    int* __restrict__ row_ptr, int* __restrict__ srcs,
    float* __restrict__ dinv, int n) {
    __shared__ int cnt[NPB];
    __shared__ int scn[NPB];
    __shared__ int cur[NPB];
    int b = blockIdx.x;
    int t = threadIdx.x;
    int node0 = b << 7;
    int p0 = bucket_ptr[b], p1 = bucket_ptr[b + 1];
    if (t < NPB) cnt[t] = 0;
    __syncthreads();
    for (int i = p0 + t; i < p1; i += 256) {
        int dlow = (int)(pairs[i] >> 17) & 127;
        atomicAdd(&cnt[dlow], 1);
    }
    __syncthreads();
    if (t < NPB) scn[t] = cnt[t];
    __syncthreads();
    for (int off = 1; off < NPB; off <<= 1) {
        int v = (t < NPB && t >= off) ? scn[t - off] : 0;
        __syncthreads();
        if (t < NPB) scn[t] += v;
        __syncthreads();
    }
    if (t < NPB) {
        int incl = scn[t];
        int excl = incl - cnt[t];
        int start = p0 + excl;
        cur[t] = start;
        int node = node0 + t;
        if (node < n) {
            row_ptr[node] = start;
            dinv[node] = rsqrtf((float)cnt[t]);  // deg >= 1 (self-loop)
            if (node == n - 1) row_ptr[n] = p0 + incl;
        }
    }
    __syncthreads();
    for (int i = p0 + t; i < p1; i += 256) {
        unsigned int pr = pairs[i];
        int pos = atomicAdd(&cur[(pr >> 17) & 127], 1);
        srcs[pos] = (int)(pr & 0x1FFFFu);
    }
}

// ---------------------------------------------------------------------------
// GEMM1: G[r][:] = bf16( dinv[r] * (A @ W)[r][:] ), A: Mx128 f32 (split-A).
// No LDS: each wave's 16 A-rows are private -> load fragments from global.
// mfma_f32_16x16x32_bf16 layouts (HW-verified, guide m89/m91):
//   A: lane holds A[m=lane&15][k=(lane>>4)*8 + j]
//   B: lane holds B[k=(lane>>4)*8 + j][n=lane&15]   (Wp is [n][k] bf16)
//   C/D: col=lane&15, row=(lane>>4)*4 + reg
// ---------------------------------------------------------------------------
__global__ __launch_bounds__(256) void k_gemm1(
    const float* __restrict__ A, const ushort_t* __restrict__ Wp,
    const float* __restrict__ dinv, ushort_t* __restrict__ G, int M) {
    int t = threadIdx.x;
    int row0 = blockIdx.x * 64;
    int wv = t >> 6;
    int lane = t & 63;
    int m = lane & 15;
    int quad = lane >> 4;

    int gr_row = row0 + wv * 16 + m;
    int gcl = gr_row < M ? gr_row : M - 1;
    const float* ap = A + (size_t)gcl * 128 + quad * 8;

    f32x4 acc[8];
#pragma unroll
    for (int c = 0; c < 8; c++) acc[c] = (f32x4){0.f, 0.f, 0.f, 0.f};

#pragma unroll
    for (int ks = 0; ks < 4; ks++) {
        int kb = ks * 32 + quad * 8;
        float xs[8];
        *(float4*)&xs[0] = *(const float4*)(ap + ks * 32);
        *(float4*)&xs[4] = *(const float4*)(ap + ks * 32 + 4);
        short8 ahi, alo;
#pragma unroll
        for (int j = 0; j < 8; j++) {
            unsigned short h = f32_to_bf16_rne(xs[j]);
            ahi[j] = (short)h;
            float hf = __uint_as_float((unsigned int)h << 16);
            alo[j] = (short)f32_to_bf16_rne(xs[j] - hf);
        }
#pragma unroll
        for (int c = 0; c < 8; c++) {
            short8 b8 = *(const short8*)(Wp + (size_t)(c * 16 + m) * 128 + kb);
            acc[c] = __builtin_amdgcn_mfma_f32_16x16x32_bf16(ahi, b8, acc[c], 0, 0, 0);
            acc[c] = __builtin_amdgcn_mfma_f32_16x16x32_bf16(alo, b8, acc[c], 0, 0, 0);
        }
    }

    int rbase = row0 + wv * 16 + quad * 4;
#pragma unroll
    for (int reg = 0; reg < 4; reg++) {
        int gr = rbase + reg;
        if (gr < M) {
            float dv = dinv[gr];
#pragma unroll
            for (int c = 0; c < 8; c++)
                G[(size_t)gr * 128 + c * 16 + m] = f32_to_bf16_rne(acc[c][reg] * dv);
        }
    }
}

// ---------------------------------------------------------------------------
// GEMM2: in-place actG2[r][:] = bf16( dinv[r] * (act @ W2)[r][:] ).
// act rows are wave-private (block = 64 rows, wave = 16 rows); in a wave all
// A-loads complete (MFMA data dep) before epilogue stores -> in-place is safe.
// Clamped tail rows may read racing data but their results are discarded.
// NOTE: actG2 deliberately NOT __restrict__ (true aliasing).
// ---------------------------------------------------------------------------
__global__ __launch_bounds__(256) void k_gemm2(
    ushort_t* actG2, const ushort_t* __restrict__ Wp,
    const float* __restrict__ dinv, int M) {
    int t = threadIdx.x;
    int row0 = blockIdx.x * 64;
    int wv = t >> 6;
    int lane = t & 63;
    int m = lane & 15;
    int quad = lane >> 4;

    int gr_row = row0 + wv * 16 + m;
    int gcl = gr_row < M ? gr_row : M - 1;
    const ushort_t* ap = actG2 + (size_t)gcl * 128;

    f32x4 acc[8];
#pragma unroll
    for (int c = 0; c < 8; c++) acc[c] = (f32x4){0.f, 0.f, 0.f, 0.f};

#pragma unroll
    for (int ks = 0; ks < 4; ks++) {
        int kb = ks * 32 + quad * 8;
        short8 a8 = *(const short8*)(ap + kb);
#pragma unroll
        for (int c = 0; c < 8; c++) {
            short8 b8 = *(const short8*)(Wp + (size_t)(c * 16 + m) * 128 + kb);
            acc[c] = __builtin_amdgcn_mfma_f32_16x16x32_bf16(a8, b8, acc[c], 0, 0, 0);
        }
    }

    int rbase = row0 + wv * 16 + quad * 4;
#pragma unroll
    for (int reg = 0; reg < 4; reg++) {
        int gr = rbase + reg;
        if (gr < M) {
            float dv = dinv[gr];
#pragma unroll
            for (int c = 0; c < 8; c++)
                actG2[(size_t)gr * 128 + c * 16 + m] = f32_to_bf16_rne(acc[c][reg] * dv);
        }
    }
}

// Aggregate 1: act = bf16(relu(dinv*sum(G1[src]) + b1)). One wave per node,
// 2 channels/lane; unroll-8 for memory-level parallelism.
__global__ __launch_bounds__(256) void k_agg1(
    const int* __restrict__ row_ptr, const int* __restrict__ srcs,
    const ushort_t* __restrict__ G, const float* __restrict__ dinv,
    const float* __restrict__ bias, unsigned int* __restrict__ ActOut, int n) {
    int wid = (blockIdx.x * 256 + threadIdx.x) >> 6;
    int lane = threadIdx.x & 63;
    if (wid >= n) return;
    int beg = row_ptr[wid], end = row_ptr[wid + 1];
    int c = lane * 2;
    float a0 = 0.f, a1 = 0.f;
    int p = beg;
    for (; p + 8 <= end; p += 8) {
        unsigned int u[8];
#pragma unroll
        for (int j = 0; j < 8; j++) {
            int s = srcs[p + j];
            u[j] = *(const unsigned int*)(G + (size_t)s * 128 + c);
        }
#pragma unroll
        for (int j = 0; j < 8; j++) {
            a0 += __uint_as_float(u[j] << 16);
            a1 += __uint_as_float(u[j] & 0xffff0000u);
        }
    }
    for (; p + 4 <= end; p += 4) {
        unsigned int u[4];
#pragma unroll
        for (int j = 0; j < 4; j++) {
            int s = srcs[p + j];
            u[j] = *(const unsigned int*)(G + (size_t)s * 128 + c);
        }
#pragma unroll
        for (int j = 0; j < 4; j++) {
            a0 += __uint_as_float(u[j] << 16);
            a1 += __uint_as_float(u[j] & 0xffff0000u);
        }
    }
    for (; p < end; p++) {
        int s = srcs[p];
        unsigned int u = *(const unsigned int*)(G + (size_t)s * 128 + c);
        a0 += __uint_as_float(u << 16);
        a1 += __uint_as_float(u & 0xffff0000u);
    }
    float dv = dinv[wid];
    a0 = fmaxf(fmaf(a0, dv, bias[c]), 0.f);
    a1 = fmaxf(fmaf(a1, dv, bias[c + 1]), 0.f);
    unsigned int uo = (unsigned int)f32_to_bf16_rne(a0) |
                      ((unsigned int)f32_to_bf16_rne(a1) << 16);
    ActOut[(size_t)wid * 64 + lane] = uo;
}

// Aggregate 2: out = dinv*sum(G2[src]) + b2 (f32, nontemporal final store).
__global__ __launch_bounds__(256) void k_agg2(
    const int* __restrict__ row_ptr, const int* __restrict__ srcs,
    const ushort_t* __restrict__ G, const float* __restrict__ dinv,
    const float* __restrict__ bias, float* __restrict__ Out, int n) {
    int wid = (blockIdx.x * 256 + threadIdx.x) >> 6;
    int lane = threadIdx.x & 63;
    if (wid >= n) return;
    int beg = row_ptr[wid], end = row_ptr[wid + 1];
    int c = lane * 2;
    float a0 = 0.f, a1 = 0.f;
    int p = beg;
    for (; p + 8 <= end; p += 8) {
        unsigned int u[8];
#pragma unroll
        for (int j = 0; j < 8; j++) {
            int s = srcs[p + j];
            u[j] = *(const unsigned int*)(G + (size_t)s * 128 + c);
        }
#pragma unroll
        for (int j = 0; j < 8; j++) {
            a0 += __uint_as_float(u[j] << 16);
            a1 += __uint_as_float(u[j] & 0xffff0000u);
        }
    }
    for (; p + 4 <= end; p += 4) {
        unsigned int u[4];
#pragma unroll
        for (int j = 0; j < 4; j++) {
            int s = srcs[p + j];
            u[j] = *(const unsigned int*)(G + (size_t)s * 128 + c);
        }
#pragma unroll
        for (int j = 0; j < 4; j++) {
            a0 += __uint_as_float(u[j] << 16);
            a1 += __uint_as_float(u[j] & 0xffff0000u);
        }
    }
    for (; p < end; p++) {
        int s = srcs[p];
        unsigned int u = *(const unsigned int*)(G + (size_t)s * 128 + c);
        a0 += __uint_as_float(u << 16);
        a1 += __uint_as_float(u & 0xffff0000u);
    }
    float dv = dinv[wid];
    a0 = fmaf(a0, dv, bias[c]);
    a1 = fmaf(a1, dv, bias[c + 1]);
    unsigned long long uv = ((unsigned long long)__float_as_uint(a1) << 32) |
                            (unsigned long long)__float_as_uint(a0);
    __builtin_nontemporal_store(uv, (unsigned long long*)(Out + (size_t)wid * 128 + c));
}

extern "C" void kernel_launch(void* const* d_in, const int* in_sizes, int n_in,
                              void* d_out, int out_size, void* d_ws, size_t ws_size,
                              hipStream_t stream) {
    const float* x  = (const float*)d_in[0];
    const int*   ei = (const int*)d_in[1];
    const float* W1 = (const float*)d_in[2];
    const float* b1 = (const float*)d_in[3];
    const float* W2 = (const float*)d_in[4];
    const float* b2 = (const float*)d_in[5];
    float* out = (float*)d_out;

    const int C = 128;
    const int N = in_sizes[0] / C;
    const int E = in_sizes[1] / 2;
    const int* src = ei;
    const int* dst = ei + E;
    const int total = E + N;
    const int nbp = (N + NPB - 1) >> 7;                 // buckets (782)
    const int T = (total + PART_TILE - 1) / PART_TILE;  // tiles (202)

    char* ws = (char*)d_ws;
    size_t off = 0;
    auto alloc = [&](size_t bytes) -> void* {
        void* p = ws + off;
        off = (off + bytes + 511) & ~(size_t)511;
        return p;
    };
    int*   Cmat       = (int*)alloc((size_t)T * nbp * 4);       // ~632 KB
    int*   colsum     = (int*)alloc((size_t)nbp * 4);
    int*   bucket_ptr = (int*)alloc((size_t)(nbp + 1) * 4);
    int*   row_ptr    = (int*)alloc(((size_t)N + 1) * 4);
    float* dinv       = (float*)alloc((size_t)N * 4);
    int*   srcs       = (int*)alloc((size_t)total * 4);
    ushort_t* Wp1     = (ushort_t*)alloc(128 * 128 * 2);
    ushort_t* Wp2     = (ushort_t*)alloc(128 * 128 * 2);
    ushort_t* G1      = (ushort_t*)alloc((size_t)N * C * 2);
    // act/G2 (in-place, N*C*2) shares with pairs (total*4): pairs dead
    // after k_build, act written by k_agg1 afterwards.
    size_t ab = (size_t)N * C * 2, pb = (size_t)total * 4;
    void* shared = alloc(ab > pb ? ab : pb);
    ushort_t* actG2 = (ushort_t*)shared;
    unsigned int* pairs = (unsigned int*)shared;

    // ---- weight prep + radix CSR build ----
    k_wprep<<<128, 256, 0, stream>>>(W1, W2, Wp1, Wp2);
    k_hist_tiles<<<T, 256, 0, stream>>>(dst, Cmat, E, nbp, total);
    k_col_scan<<<(nbp + 255) / 256, 256, 0, stream>>>(Cmat, colsum, T, nbp);
    k_bucket_scan<<<1, 256, 0, stream>>>(colsum, bucket_ptr, nbp, total);
    k_partition<<<T, 256, 0, stream>>>(src, dst, Cmat, bucket_ptr, pairs, E, nbp, total);
    k_build<<<nbp, 256, 0, stream>>>(pairs, bucket_ptr, row_ptr, srcs, dinv, N);

    // ---- layer 1: G1 = bf16(dinv*(x@W1)); act = bf16(relu(dinv*sum+b1)) ----
    k_gemm1<<<(N + 63) / 64, 256, 0, stream>>>(x, Wp1, dinv, G1, N);
    k_agg1<<<(N + 3) / 4, 256, 0, stream>>>(row_ptr, srcs, G1, dinv, b1,
                                            (unsigned int*)actG2, N);

    // ---- layer 2: G2 = bf16(dinv*(act@W2)) in-place; out = dinv*sum+b2 ----
    k_gemm2<<<(N + 63) / 64, 256, 0, stream>>>(actG2, Wp2, dinv, N);
    k_agg2<<<(N + 3) / 4, 256, 0, stream>>>(row_ptr, srcs, actG2, dinv, b2, out, N);
}